// Round 2
// baseline (21.846 us; speedup 1.0000x reference)
//
#include <hip/hip_runtime.h>
#include <math.h>

#define BATCH  1024
#define SEQ    200
#define DIM    128
#define NCHUNK 5
#define CH     40   // sequence positions per chunk (NCHUNK*CH >= SEQ)

__global__ __launch_bounds__(256) void dft_layer_kernel(
    const int* __restrict__ seqs,
    const float* __restrict__ emb,
    float* __restrict__ out)
{
    const int bid = blockIdx.x;
    const int b   = bid / NCHUNK;
    const int c   = bid % NCHUNK;
    const int tid = threadIdx.x;

    __shared__ int   s_seq[SEQ];
    __shared__ float s_mag[SEQ];
    __shared__ int   s_match[SEQ];
    __shared__ int   s_cnt[2];        // [0]=L, [1]=M
    __shared__ float s_sum;
    __shared__ float s_part[8][DIM];  // 8 s-subgroups x 128 floats

    if (tid < 2)  s_cnt[tid] = 0;
    if (tid == 0) s_sum = 0.0f;
    if (tid < SEQ) s_seq[tid] = seqs[b * SEQ + tid];
    __syncthreads();

    // L = number of nonzero tokens (contiguous at front)
    bool nz = (tid < SEQ) && (s_seq[tid] != 0);
    unsigned long long bal = __ballot(nz);
    if ((tid & 63) == 0) atomicAdd(&s_cnt[0], __popcll(bal));
    __syncthreads();

    const int L = s_cnt[0];
    // this chunk covers s in [c*CH, c*CH+CH) intersect [1, L)
    if (c * CH >= L) return;   // block-uniform early exit (no work here)

    const int last = s_seq[L - 1];

    // positions where token == last (nonzeros of `binary`), usually M==1
    if (tid < L && s_seq[tid] == last) {
        int idx = atomicAdd(&s_cnt[1], 1);
        s_match[idx] = tid;
    }
    __syncthreads();
    const int   M  = s_cnt[1];
    const float Lf = (float)L;

    // per-k DFT magnitude over the M nonzeros; keep k < L-1, zero elsewhere
    float mag = 0.0f;
    if (tid < SEQ) {
        if (tid < L - 1) {
            float re = 0.0f, im = 0.0f;
            const float kf = (float)tid;
            for (int m = 0; m < M; ++m) {
                float kn    = kf * (float)s_match[m];
                float theta = (-6.2831855f * kn) / Lf;  // match ref op order
                float sv, cv;
                sincosf(theta, &sv, &cv);
                re += cv;
                im += sv;
            }
            mag = sqrtf(re * re + im * im);
        }
        s_mag[tid] = mag;
    }
    // block-reduce sum of mag (s_mag[k]=0 for k>=L-1, so full-row sum is fine)
    float v = mag;
    #pragma unroll
    for (int o = 32; o > 0; o >>= 1) v += __shfl_down(v, o, 64);
    if ((tid & 63) == 0) atomicAdd(&s_sum, v);
    __syncthreads();
    const float invSum = 1.0f / s_sum;

    // partial: sum over s in this chunk (s>=1, s<L) of mag[s-1]*emb[b,s,:]
    const int sLo = (c == 0) ? 1 : c * CH;
    const int sHi = min(c * CH + CH, L);

    const int c4 = tid & 31;         // float4 chunk index within emb row
    const int g  = tid >> 5;         // s-subgroup 0..7
    const float4* ebase = (const float4*)(emb + (size_t)b * SEQ * DIM);
    float4 acc = make_float4(0.f, 0.f, 0.f, 0.f);
    for (int s = sLo + g; s < sHi; s += 8) {
        float  w = s_mag[s - 1];
        float4 e = ebase[s * 32 + c4];
        acc.x += w * e.x; acc.y += w * e.y; acc.z += w * e.z; acc.w += w * e.w;
    }
    {
        float* p = &s_part[g][c4 << 2];
        p[0] = acc.x; p[1] = acc.y; p[2] = acc.z; p[3] = acc.w;
    }
    __syncthreads();
    if (tid < DIM) {
        float r = 0.0f;
        #pragma unroll
        for (int gg = 0; gg < 8; ++gg) r += s_part[gg][tid];
        atomicAdd(&out[(size_t)b * DIM + tid], r * invSum);
    }
}

extern "C" void kernel_launch(void* const* d_in, const int* in_sizes, int n_in,
                              void* d_out, int out_size, void* d_ws, size_t ws_size,
                              hipStream_t stream) {
    const int*   seqs = (const int*)d_in[0];
    const float* emb  = (const float*)d_in[1];
    float*       out  = (float*)d_out;
    hipMemsetAsync(out, 0, (size_t)out_size * sizeof(float), stream);
    dft_layer_kernel<<<BATCH * NCHUNK, 256, 0, stream>>>(seqs, emb, out);
}

// Round 4
// 15.944 us; speedup vs baseline: 1.3702x; 1.3702x over previous
//
#include <hip/hip_runtime.h>
#include <math.h>

#define BATCH 1024
#define SEQ   200
#define DIM   128
#define NT    512

__global__ __launch_bounds__(NT, 8) void dft_layer_kernel(
    const int* __restrict__ seqs,
    const float* __restrict__ emb,
    float* __restrict__ out)
{
    const int b   = blockIdx.x;
    const int tid = threadIdx.x;

    __shared__ int   s_seq[SEQ];
    __shared__ float s_mag[SEQ];
    __shared__ int   s_match[SEQ];
    __shared__ int   s_cnt[2];         // [0]=L, [1]=M
    __shared__ float s_sum;
    __shared__ float s_part[16][DIM];  // 16 s-groups x 128 floats (8 KB)

    if (tid < 2)  s_cnt[tid] = 0;
    if (tid == 0) s_sum = 0.0f;
    int tok = 0;
    if (tid < SEQ) { tok = seqs[b * SEQ + tid]; s_seq[tid] = tok; }
    __syncthreads();

    // L = count of nonzero tokens (contiguous at front)
    unsigned long long bal = __ballot((tid < SEQ) && (tok != 0));
    if ((tid & 63) == 0) atomicAdd(&s_cnt[0], __popcll(bal));
    __syncthreads();
    const int L    = s_cnt[0];
    const int last = s_seq[L - 1];

    // positions where token == last (nonzeros of `binary`); M==1 for ~99.9% rows
    if ((tid < L) && (tok == last)) {
        int idx = atomicAdd(&s_cnt[1], 1);
        s_match[idx] = tid;
    }
    __syncthreads();
    const int M = s_cnt[1];

    float invSum;
    if (M == 1) {
        // single impulse at n=L-1 -> |DFT_k| == 1 for all k -> uniform weights
        invSum = 1.0f / (float)(L - 1);
    } else {
        // rare path: explicit DFT magnitude over the M impulses
        const float Lf = (float)L;
        float mag = 0.0f;
        if (tid < L - 1) {
            float re = 0.0f, im = 0.0f;
            const float kf = (float)tid;
            for (int m = 0; m < M; ++m) {
                float rev = kf * (float)s_match[m] / Lf;  // theta in revolutions
                rev -= floorf(rev);                        // sign dropped: mag is even
                float th = 6.2831855f * rev;
                re += __cosf(th);
                im += __sinf(th);
            }
            mag = sqrtf(re * re + im * im);
        }
        if (tid < SEQ) s_mag[tid] = mag;
        float v = mag;
        #pragma unroll
        for (int o = 32; o > 0; o >>= 1) v += __shfl_down(v, o, 64);
        if ((tid & 63) == 0) atomicAdd(&s_sum, v);
        __syncthreads();                    // block-uniform branch: legal
        invSum = 1.0f / s_sum;
    }

    // gather: out[b,:] = invSum * sum_{s=1}^{L-1} w[s-1] * emb[b,s,:]
    const int c4 = tid & 31;   // float4 chunk within the 128-float row
    const int g  = tid >> 5;   // s-group 0..15
    const float4* ebase = (const float4*)(emb + (size_t)b * SEQ * DIM);
    float4 a0 = make_float4(0.f, 0.f, 0.f, 0.f);
    float4 a1 = make_float4(0.f, 0.f, 0.f, 0.f);

    if (M == 1) {
        int s = 1 + g;
        for (; s + 16 < L; s += 32) {
            float4 e0 = ebase[s * 32 + c4];
            float4 e1 = ebase[(s + 16) * 32 + c4];
            a0.x += e0.x; a0.y += e0.y; a0.z += e0.z; a0.w += e0.w;
            a1.x += e1.x; a1.y += e1.y; a1.z += e1.z; a1.w += e1.w;
        }
        if (s < L) {
            float4 e0 = ebase[s * 32 + c4];
            a0.x += e0.x; a0.y += e0.y; a0.z += e0.z; a0.w += e0.w;
        }
    } else {
        int s = 1 + g;
        for (; s + 16 < L; s += 32) {
            float w0 = s_mag[s - 1];
            float w1 = s_mag[s + 15];
            float4 e0 = ebase[s * 32 + c4];
            float4 e1 = ebase[(s + 16) * 32 + c4];
            a0.x += w0 * e0.x; a0.y += w0 * e0.y; a0.z += w0 * e0.z; a0.w += w0 * e0.w;
            a1.x += w1 * e1.x; a1.y += w1 * e1.y; a1.z += w1 * e1.z; a1.w += w1 * e1.w;
        }
        if (s < L) {
            float w0 = s_mag[s - 1];
            float4 e0 = ebase[s * 32 + c4];
            a0.x += w0 * e0.x; a0.y += w0 * e0.y; a0.z += w0 * e0.z; a0.w += w0 * e0.w;
        }
    }
    a0.x += a1.x; a0.y += a1.y; a0.z += a1.z; a0.w += a1.w;
    {
        float* p = &s_part[g][c4 << 2];
        p[0] = a0.x; p[1] = a0.y; p[2] = a0.z; p[3] = a0.w;
    }
    __syncthreads();
    if (tid < DIM) {
        float r = 0.0f;
        #pragma unroll
        for (int gg = 0; gg < 16; ++gg) r += s_part[gg][tid];
        out[(size_t)b * DIM + tid] = r * invSum;
    }
}

extern "C" void kernel_launch(void* const* d_in, const int* in_sizes, int n_in,
                              void* d_out, int out_size, void* d_ws, size_t ws_size,
                              hipStream_t stream) {
    const int*   seqs = (const int*)d_in[0];
    const float* emb  = (const float*)d_in[1];
    float*       out  = (float*)d_out;
    dft_layer_kernel<<<BATCH, NT, 0, stream>>>(seqs, emb, out);
}

// Round 7
// 14.809 us; speedup vs baseline: 1.4752x; 1.0766x over previous
//
#include <hip/hip_runtime.h>
#include <math.h>

#define BATCH 1024
#define SEQ   200
#define DIM   128
#define NT    512

__global__ __launch_bounds__(NT, 8) void dft_layer_kernel(
    const int* __restrict__ seqs,
    const float* __restrict__ emb,
    float* __restrict__ out)
{
    const int b   = blockIdx.x;
    const int tid = threadIdx.x;
    const int c4  = tid & 31;   // float4 chunk within the 128-float row
    const int g   = tid >> 5;   // s-group 0..15

    __shared__ int   s_seq[SEQ];
    __shared__ float s_mag[SEQ];
    __shared__ int   s_match[SEQ];
    __shared__ int   s_cnt[2];         // [0]=L, [1]=M
    __shared__ float s_sum;
    __shared__ float s_part[16][DIM];  // 16 s-groups x 128 floats (8 KB)

    const float4* ebase = (const float4*)(emb + (size_t)b * SEQ * DIM);

    if (tid < 2)  s_cnt[tid] = 0;
    if (tid == 0) s_sum = 0.0f;

    // issue seq load first, then speculative first-2-iteration gather loads
    // (rows 1..32 always exist; masked later by s<L). These stay in flight
    // through the whole preamble -> preamble latency is hidden.
    int tok = 0;
    if (tid < SEQ) tok = seqs[b * SEQ + tid];
    const int sp0 = 1 + g, sp1 = 17 + g;
    float4 p0 = ebase[sp0 * 32 + c4];
    float4 p1 = ebase[sp1 * 32 + c4];

    if (tid < SEQ) s_seq[tid] = tok;
    __syncthreads();

    // L = count of nonzero tokens (contiguous at front)
    unsigned long long bal = __ballot((tid < SEQ) && (tok != 0));
    if ((tid & 63) == 0) atomicAdd(&s_cnt[0], __popcll(bal));
    __syncthreads();
    const int L    = s_cnt[0];
    const int last = s_seq[L - 1];

    // positions where token == last (nonzeros of `binary`); M==1 for ~99.9% rows
    if ((tid < L) && (tok == last)) {
        int idx = atomicAdd(&s_cnt[1], 1);
        s_match[idx] = tid;
    }
    __syncthreads();
    const int M = s_cnt[1];

    float invSum;
    if (M == 1) {
        // single impulse at n=L-1 -> |DFT_k| == 1 for all k -> uniform weights
        invSum = 1.0f / (float)(L - 1);
    } else {
        // rare path: explicit DFT magnitude over the M impulses
        const float Lf = (float)L;
        float mag = 0.0f;
        if (tid < L - 1) {
            float re = 0.0f, im = 0.0f;
            const float kf = (float)tid;
            for (int m = 0; m < M; ++m) {
                float rev = kf * (float)s_match[m] / Lf;  // theta in revolutions
                rev -= floorf(rev);                        // sign dropped: |.| is even
                float th = 6.2831855f * rev;
                re += __cosf(th);
                im += __sinf(th);
            }
            mag = sqrtf(re * re + im * im);
        }
        if (tid < SEQ) s_mag[tid] = mag;
        float v = mag;
        #pragma unroll
        for (int o = 32; o > 0; o >>= 1) v += __shfl_down(v, o, 64);
        if ((tid & 63) == 0) atomicAdd(&s_sum, v);
        __syncthreads();                    // block-uniform branch: legal
        invSum = 1.0f / s_sum;
    }

    // gather: out[b,:] = invSum * sum_{s=1}^{L-1} w[s-1] * emb[b,s,:]
    float4 a0 = make_float4(0.f, 0.f, 0.f, 0.f);
    float4 a1 = make_float4(0.f, 0.f, 0.f, 0.f);

    if (M == 1) {
        // weights uniform: mask speculative rows by s<L
        float w0 = (sp0 < L) ? 1.0f : 0.0f;
        float w1 = (sp1 < L) ? 1.0f : 0.0f;
        a0.x = w0 * p0.x; a0.y = w0 * p0.y; a0.z = w0 * p0.z; a0.w = w0 * p0.w;
        a1.x = w1 * p1.x; a1.y = w1 * p1.y; a1.z = w1 * p1.z; a1.w = w1 * p1.w;
        int s = 33 + g;
        for (; s + 48 < L; s += 64) {   // unroll-4: 4 loads in flight
            float4 e0 = ebase[(s     ) * 32 + c4];
            float4 e1 = ebase[(s + 16) * 32 + c4];
            float4 e2 = ebase[(s + 32) * 32 + c4];
            float4 e3 = ebase[(s + 48) * 32 + c4];
            a0.x += e0.x; a0.y += e0.y; a0.z += e0.z; a0.w += e0.w;
            a1.x += e1.x; a1.y += e1.y; a1.z += e1.z; a1.w += e1.w;
            a0.x += e2.x; a0.y += e2.y; a0.z += e2.z; a0.w += e2.w;
            a1.x += e3.x; a1.y += e3.y; a1.z += e3.z; a1.w += e3.w;
        }
        for (; s + 16 < L; s += 32) {   // unroll-2 tail
            float4 e0 = ebase[(s     ) * 32 + c4];
            float4 e1 = ebase[(s + 16) * 32 + c4];
            a0.x += e0.x; a0.y += e0.y; a0.z += e0.z; a0.w += e0.w;
            a1.x += e1.x; a1.y += e1.y; a1.z += e1.z; a1.w += e1.w;
        }
        if (s < L) {
            float4 e0 = ebase[s * 32 + c4];
            a0.x += e0.x; a0.y += e0.y; a0.z += e0.z; a0.w += e0.w;
        }
    } else {
        float w0 = (sp0 < L) ? s_mag[sp0 - 1] : 0.0f;
        float w1 = (sp1 < L) ? s_mag[sp1 - 1] : 0.0f;
        a0.x = w0 * p0.x; a0.y = w0 * p0.y; a0.z = w0 * p0.z; a0.w = w0 * p0.w;
        a1.x = w1 * p1.x; a1.y = w1 * p1.y; a1.z = w1 * p1.z; a1.w = w1 * p1.w;
        int s = 33 + g;
        for (; s + 48 < L; s += 64) {
            float u0 = s_mag[s - 1],  u1 = s_mag[s + 15];
            float u2 = s_mag[s + 31], u3 = s_mag[s + 47];
            float4 e0 = ebase[(s     ) * 32 + c4];
            float4 e1 = ebase[(s + 16) * 32 + c4];
            float4 e2 = ebase[(s + 32) * 32 + c4];
            float4 e3 = ebase[(s + 48) * 32 + c4];
            a0.x += u0 * e0.x; a0.y += u0 * e0.y; a0.z += u0 * e0.z; a0.w += u0 * e0.w;
            a1.x += u1 * e1.x; a1.y += u1 * e1.y; a1.z += u1 * e1.z; a1.w += u1 * e1.w;
            a0.x += u2 * e2.x; a0.y += u2 * e2.y; a0.z += u2 * e2.z; a0.w += u2 * e2.w;
            a1.x += u3 * e3.x; a1.y += u3 * e3.y; a1.z += u3 * e3.z; a1.w += u3 * e3.w;
        }
        for (; s + 16 < L; s += 32) {
            float u0 = s_mag[s - 1], u1 = s_mag[s + 15];
            float4 e0 = ebase[(s     ) * 32 + c4];
            float4 e1 = ebase[(s + 16) * 32 + c4];
            a0.x += u0 * e0.x; a0.y += u0 * e0.y; a0.z += u0 * e0.z; a0.w += u0 * e0.w;
            a1.x += u1 * e1.x; a1.y += u1 * e1.y; a1.z += u1 * e1.z; a1.w += u1 * e1.w;
        }
        if (s < L) {
            float u0 = s_mag[s - 1];
            float4 e0 = ebase[s * 32 + c4];
            a0.x += u0 * e0.x; a0.y += u0 * e0.y; a0.z += u0 * e0.z; a0.w += u0 * e0.w;
        }
    }

    a0.x += a1.x; a0.y += a1.y; a0.z += a1.z; a0.w += a1.w;
    {
        float* p = &s_part[g][c4 << 2];
        p[0] = a0.x; p[1] = a0.y; p[2] = a0.z; p[3] = a0.w;
    }
    __syncthreads();
    if (tid < DIM) {
        float r = 0.0f;
        #pragma unroll
        for (int gg = 0; gg < 16; ++gg) r += s_part[gg][tid];
        out[(size_t)b * DIM + tid] = r * invSum;
    }
}

extern "C" void kernel_launch(void* const* d_in, const int* in_sizes, int n_in,
                              void* d_out, int out_size, void* d_ws, size_t ws_size,
                              hipStream_t stream) {
    const int*   seqs = (const int*)d_in[0];
    const float* emb  = (const float*)d_in[1];
    float*       out  = (float*)d_out;
    dft_layer_kernel<<<BATCH, NT, 0, stream>>>(seqs, emb, out);
}